// Round 3
// baseline (538.342 us; speedup 1.0000x reference)
//
#include <hip/hip_runtime.h>

#define CIN  128
#define COUT 64
#define KVOL 4
#define TMR  128          // rows per block (4 waves x 32 rows)
#define BN_EPS 1e-5f

typedef __bf16 bf16x8 __attribute__((ext_vector_type(8)));
typedef float  f32x4  __attribute__((ext_vector_type(4)));
typedef float  f32x8  __attribute__((ext_vector_type(8)));

// ws layout (bytes):
//   128  float gsum[64]
//   384  float gsq[64]
//   1024 __bf16 wfrag[4][4][4][64][8]   (64 KB, fragment-ordered weights)

// wfrag[k][f][ks][lane][j] = W[k][ ks*32 + (lane>>4)*8 + j ][ f*16 + (lane&15) ]
__global__ void k_prepw(const float* __restrict__ weight, __bf16* __restrict__ wfrag) {
  int id = blockIdx.x * 256 + threadIdx.x;       // 0..32767
  int j  = id & 7;
  int l  = (id >> 3) & 63;
  int ks = (id >> 9) & 3;
  int f  = (id >> 11) & 3;
  int k  = id >> 13;
  int kk = ks * 32 + (l >> 4) * 8 + j;
  int n  = f * 16 + (l & 15);
  wfrag[id] = (__bf16)weight[(k * CIN + kk) * COUT + n];
}

__device__ inline bf16x8 sel8(bool c, bf16x8 a, bf16x8 z) { return c ? a : z; }

__global__ __launch_bounds__(256, 4)
void k_gemm(const float* __restrict__ feats, const int* __restrict__ in_idx,
            const int* __restrict__ kidx, const __bf16* __restrict__ wfrag,
            float* __restrict__ out, float* __restrict__ gsum, float* __restrict__ gsq,
            int M) {
  int t  = threadIdx.x;
  int w  = t >> 6, l = t & 63;
  int lr = l & 15, lg = l >> 4;
  int m0 = blockIdx.x * TMR + w * 32;      // this wave's 32 rows

  int r0 = m0 + lr, r1 = m0 + 16 + lr;
  bool v0 = r0 < M, v1 = r1 < M;
  int kA0 = v0 ? kidx[r0] : -1;
  int kA1 = v1 ? kidx[r1] : -1;
  long g0 = v0 ? in_idx[r0] : 0;
  long g1 = v1 ? in_idx[r1] : 0;

  // ---- A fragments: direct global gather, f32 -> bf16 in-register ----
  // a[mf][ks] covers k = ks*32 + lg*8 .. +8 of row (m0 + mf*16 + lr)
  bf16x8 a[2][4];
  {
    const float* p0 = feats + g0 * CIN + lg * 8;
    const float* p1 = feats + g1 * CIN + lg * 8;
    #pragma unroll
    for (int ks = 0; ks < 4; ++ks) {
      f32x8 f0 = *(const f32x8*)(p0 + ks * 32);
      f32x8 f1 = *(const f32x8*)(p1 + ks * 32);
      a[0][ks] = __builtin_convertvector(f0, bf16x8);
      a[1][ks] = __builtin_convertvector(f1, bf16x8);
    }
  }

  f32x4 acc[2][4];
  #pragma unroll
  for (int mf = 0; mf < 2; ++mf)
    #pragma unroll
    for (int f = 0; f < 4; ++f)
      acc[mf][f] = (f32x4){0.f, 0.f, 0.f, 0.f};

  f32x8 zf = {0.f,0.f,0.f,0.f,0.f,0.f,0.f,0.f};
  bf16x8 z8 = __builtin_convertvector(zf, bf16x8);

  // ---- K-vol loop: masked-A MFMA accumulate ----
  #pragma unroll 1
  for (int k = 0; k < KVOL; ++k) {
    const bf16x8* wp = (const bf16x8*)wfrag + (long)k * 16 * 64 + l;
    bool s0 = (kA0 == k), s1 = (kA1 == k);
    #pragma unroll
    for (int ks = 0; ks < 4; ++ks) {
      bf16x8 a0 = sel8(s0, a[0][ks], z8);
      bf16x8 a1 = sel8(s1, a[1][ks], z8);
      #pragma unroll
      for (int f = 0; f < 4; ++f) {
        bf16x8 b = wp[(f * 4 + ks) * 64];
        acc[0][f] = __builtin_amdgcn_mfma_f32_16x16x32_bf16(a0, b, acc[0][f], 0, 0, 0);
        acc[1][f] = __builtin_amdgcn_mfma_f32_16x16x32_bf16(a1, b, acc[1][f], 0, 0, 0);
      }
    }
  }

  // ---- store + per-column partial stats ----
  float s[4] = {0.f,0.f,0.f,0.f}, q[4] = {0.f,0.f,0.f,0.f};
  #pragma unroll
  for (int mf = 0; mf < 2; ++mf)
    #pragma unroll
    for (int f = 0; f < 4; ++f)
      #pragma unroll
      for (int reg = 0; reg < 4; ++reg) {
        int m = m0 + mf * 16 + lg * 4 + reg;
        float vv = acc[mf][f][reg];
        s[f] += vv; q[f] += vv * vv;            // invalid rows are exactly 0
        if (m < M) out[(long)m * COUT + f * 16 + lr] = vv;
      }

  // ---- wave-level stats reduction over the 4 lg-groups, then atomics ----
  #pragma unroll
  for (int f = 0; f < 4; ++f) {
    s[f] += __shfl_xor(s[f], 16); s[f] += __shfl_xor(s[f], 32);
    q[f] += __shfl_xor(q[f], 16); q[f] += __shfl_xor(q[f], 32);
  }
  if (lg == 0) {
    #pragma unroll
    for (int f = 0; f < 4; ++f) {
      atomicAdd(&gsum[f * 16 + lr], s[f]);
      atomicAdd(&gsq[f * 16 + lr], q[f]);
    }
  }
}

__global__ void k_norm(float* __restrict__ out,
                       const float* __restrict__ gsum, const float* __restrict__ gsq,
                       const float* __restrict__ gamma, const float* __restrict__ beta,
                       int M) {
  long total = (long)M * COUT / 4;
  long T0 = (long)blockIdx.x * blockDim.x + threadIdx.x;
  int c0 = (int)((T0 * 4) & 63);
  float4 sm = *(const float4*)&gsum[c0];
  float4 sq = *(const float4*)&gsq[c0];
  float inv = 1.0f / (float)M;
  float mx = sm.x * inv, my = sm.y * inv, mz = sm.z * inv, mw = sm.w * inv;
  float rx = rsqrtf(sq.x * inv - mx * mx + BN_EPS);
  float ry = rsqrtf(sq.y * inv - my * my + BN_EPS);
  float rz = rsqrtf(sq.z * inv - mz * mz + BN_EPS);
  float rw = rsqrtf(sq.w * inv - mw * mw + BN_EPS);
  float4 ga = *(const float4*)&gamma[c0];
  float4 be = *(const float4*)&beta[c0];
  float scx = rx * ga.x, scy = ry * ga.y, scz = rz * ga.z, scw = rw * ga.w;
  float shx = be.x - mx * scx, shy = be.y - my * scy;
  float shz = be.z - mz * scz, shw = be.w - mw * scw;
  float4* o4 = (float4*)out;
  long stride = (long)gridDim.x * blockDim.x;
  for (long j = T0; j < total; j += stride) {
    float4 v = o4[j];
    v.x = fmaxf(fmaf(v.x, scx, shx), 0.f);
    v.y = fmaxf(fmaf(v.y, scy, shy), 0.f);
    v.z = fmaxf(fmaf(v.z, scz, shz), 0.f);
    v.w = fmaxf(fmaf(v.w, scw, shw), 0.f);
    o4[j] = v;
  }
}

extern "C" void kernel_launch(void* const* d_in, const int* in_sizes, int n_in,
                              void* d_out, int out_size, void* d_ws, size_t ws_size,
                              hipStream_t stream) {
  const float* feats  = (const float*)d_in[0];
  const float* weight = (const float*)d_in[1];
  const float* gamma  = (const float*)d_in[2];
  const float* beta   = (const float*)d_in[3];
  const int*   in_idx = (const int*)d_in[4];
  const int*   kidx   = (const int*)d_in[5];
  int M = in_sizes[4];
  float* out = (float*)d_out;

  float*  gsum  = (float*)((char*)d_ws + 128);
  float*  gsq   = (float*)((char*)d_ws + 384);
  __bf16* wfrag = (__bf16*)((char*)d_ws + 1024);

  hipMemsetAsync(d_ws, 0, 1024, stream);
  k_prepw<<<128, 256, 0, stream>>>(weight, wfrag);

  int nb = (M + TMR - 1) / TMR;
  k_gemm<<<nb, 256, 0, stream>>>(feats, in_idx, kidx, wfrag, out, gsum, gsq, M);

  k_norm<<<2048, 256, 0, stream>>>(out, gsum, gsq, gamma, beta, M);
}

// Round 4
// 171.452 us; speedup vs baseline: 3.1399x; 3.1399x over previous
//
#include <hip/hip_runtime.h>

#define CIN  128
#define COUT 64
#define KVOL 4
#define TP   64           // parents per block (4 waves x 16 parents)
#define BN_EPS 1e-5f

typedef __bf16 bf16x8 __attribute__((ext_vector_type(8)));
typedef float  f32x4  __attribute__((ext_vector_type(4)));
typedef float  f32x8  __attribute__((ext_vector_type(8)));

// ws layout (bytes):
//   128    float gsum[64]
//   384    float gsq[64]
//   1024   __bf16 wfrag[4][4][4][64][8]   (64 KB, fragment-ordered weights)
//   66560  int tbl[N_IN][4]               (m index per (parent, k) or -1)

// wfrag[k][f][ks][lane][j] = W[k][ ks*32 + (lane>>4)*8 + j ][ f*16 + (lane&15) ]
__global__ void k_prepw(const float* __restrict__ weight, __bf16* __restrict__ wfrag) {
  int id = blockIdx.x * 256 + threadIdx.x;       // 0..32767
  int j  = id & 7;
  int l  = (id >> 3) & 63;
  int ks = (id >> 9) & 3;
  int f  = (id >> 11) & 3;
  int k  = id >> 13;
  int kk = ks * 32 + (l >> 4) * 8 + j;
  int n  = f * 16 + (l & 15);
  wfrag[id] = (__bf16)weight[(k * CIN + kk) * COUT + n];
}

__global__ void k_tbl(const int* __restrict__ in_idx, const int* __restrict__ kidx,
                      int M, int* __restrict__ tbl) {
  for (int m = blockIdx.x * blockDim.x + threadIdx.x; m < M;
       m += gridDim.x * blockDim.x)
    tbl[in_idx[m] * KVOL + (kidx[m] & 3)] = m;
}

__global__ __launch_bounds__(256, 4)
void k_gemm(const float* __restrict__ feats, const int* __restrict__ tbl,
            const __bf16* __restrict__ wfrag, float* __restrict__ out,
            float* __restrict__ gsum, float* __restrict__ gsq, int N_IN) {
  __shared__ char Fl[TP * 256];     // 16 KB: 64 parent rows x 128 bf16, XOR-swizzled
  int t  = threadIdx.x;
  int i0 = blockIdx.x * TP;

  // ---- stage: streaming read of 64 consecutive feat rows, cvt -> bf16 ----
  {
    int r = t >> 2, qq = t & 3;     // 4 threads per row, 32 floats each
    bool v = (i0 + r) < N_IN;
    const float* src = feats + (long)(i0 + r) * CIN + qq * 32;
    char* dst = Fl + r * 256;
    int sw = (r & 7) << 4;
    #pragma unroll
    for (int i = 0; i < 4; ++i) {
      f32x8 fv = {0.f,0.f,0.f,0.f,0.f,0.f,0.f,0.f};
      if (v) fv = *(const f32x8*)(src + i * 8);
      *(bf16x8*)(dst + ((qq * 64 + i * 16) ^ sw)) = __builtin_convertvector(fv, bf16x8);
    }
  }
  __syncthreads();

  int w  = t >> 6, l = t & 63;
  int lr = l & 15, lg = l >> 4;
  int roff = w * 16;                // this wave's 16 parent rows

  // ---- A fragments from LDS (row lr of this wave's 16) ----
  bf16x8 a[4];
  {
    const char* ap = Fl + (roff + lr) * 256;
    int sw = ((roff + lr) & 7) << 4;
    #pragma unroll
    for (int ks = 0; ks < 4; ++ks)
      a[ks] = *(const bf16x8*)(ap + ((ks * 64 + lg * 16) ^ sw));
  }

  // ---- child-row lookups: mrow[reg] = tbl[i0+roff+lg*4+reg][0..3] ----
  int4 mrow[4];
  #pragma unroll
  for (int reg = 0; reg < 4; ++reg) {
    int i = i0 + roff + lg * 4 + reg;
    mrow[reg] = (i < N_IN) ? *(const int4*)&tbl[i * 4] : make_int4(-1, -1, -1, -1);
  }

  float s[4] = {0.f,0.f,0.f,0.f}, q[4] = {0.f,0.f,0.f,0.f};

  #pragma unroll
  for (int k = 0; k < KVOL; ++k) {
    const bf16x8* wp = (const bf16x8*)wfrag + k * 1024 + l;
    f32x4 acc[4];
    #pragma unroll
    for (int f = 0; f < 4; ++f) acc[f] = (f32x4){0.f, 0.f, 0.f, 0.f};
    #pragma unroll
    for (int ks = 0; ks < 4; ++ks)
      #pragma unroll
      for (int f = 0; f < 4; ++f)
        acc[f] = __builtin_amdgcn_mfma_f32_16x16x32_bf16(a[ks], wp[(f * 4 + ks) * 64],
                                                         acc[f], 0, 0, 0);
    // scatter-store existing children + accumulate stats
    #pragma unroll
    for (int reg = 0; reg < 4; ++reg) {
      int m = (k == 0) ? mrow[reg].x : (k == 1) ? mrow[reg].y
            : (k == 2) ? mrow[reg].z : mrow[reg].w;
      if (m >= 0) {
        #pragma unroll
        for (int f = 0; f < 4; ++f) {
          float vv = acc[f][reg];
          s[f] += vv; q[f] += vv * vv;
          out[(long)m * COUT + f * 16 + lr] = vv;
        }
      }
    }
  }

  // ---- stats: shfl over lg, then block-level LDS reduce, 128 atomics/block ----
  #pragma unroll
  for (int f = 0; f < 4; ++f) {
    s[f] += __shfl_xor(s[f], 16); s[f] += __shfl_xor(s[f], 32);
    q[f] += __shfl_xor(q[f], 16); q[f] += __shfl_xor(q[f], 32);
  }
  __syncthreads();                       // Fl no longer needed
  float* redS = (float*)Fl;              // [4][64]
  float* redQ = redS + 256;              // [4][64]
  if (lg == 0) {
    #pragma unroll
    for (int f = 0; f < 4; ++f) {
      redS[w * 64 + f * 16 + lr] = s[f];
      redQ[w * 64 + f * 16 + lr] = q[f];
    }
  }
  __syncthreads();
  if (t < COUT) {
    float fs = 0.f, fq = 0.f;
    #pragma unroll
    for (int g = 0; g < 4; ++g) { fs += redS[g * 64 + t]; fq += redQ[g * 64 + t]; }
    atomicAdd(&gsum[t], fs);
    atomicAdd(&gsq[t], fq);
  }
}

__global__ void k_norm(float* __restrict__ out,
                       const float* __restrict__ gsum, const float* __restrict__ gsq,
                       const float* __restrict__ gamma, const float* __restrict__ beta,
                       int M) {
  long total = (long)M * COUT / 4;
  long T0 = (long)blockIdx.x * blockDim.x + threadIdx.x;
  int c0 = (int)((T0 * 4) & 63);
  float4 sm = *(const float4*)&gsum[c0];
  float4 sq = *(const float4*)&gsq[c0];
  float inv = 1.0f / (float)M;
  float mx = sm.x * inv, my = sm.y * inv, mz = sm.z * inv, mw = sm.w * inv;
  float rx = rsqrtf(sq.x * inv - mx * mx + BN_EPS);
  float ry = rsqrtf(sq.y * inv - my * my + BN_EPS);
  float rz = rsqrtf(sq.z * inv - mz * mz + BN_EPS);
  float rw = rsqrtf(sq.w * inv - mw * mw + BN_EPS);
  float4 ga = *(const float4*)&gamma[c0];
  float4 be = *(const float4*)&beta[c0];
  float scx = rx * ga.x, scy = ry * ga.y, scz = rz * ga.z, scw = rw * ga.w;
  float shx = be.x - mx * scx, shy = be.y - my * scy;
  float shz = be.z - mz * scz, shw = be.w - mw * scw;
  float4* o4 = (float4*)out;
  long stride = (long)gridDim.x * blockDim.x;
  for (long j = T0; j < total; j += stride) {
    float4 v = o4[j];
    v.x = fmaxf(fmaf(v.x, scx, shx), 0.f);
    v.y = fmaxf(fmaf(v.y, scy, shy), 0.f);
    v.z = fmaxf(fmaf(v.z, scz, shz), 0.f);
    v.w = fmaxf(fmaf(v.w, scw, shw), 0.f);
    o4[j] = v;
  }
}

extern "C" void kernel_launch(void* const* d_in, const int* in_sizes, int n_in,
                              void* d_out, int out_size, void* d_ws, size_t ws_size,
                              hipStream_t stream) {
  const float* feats  = (const float*)d_in[0];
  const float* weight = (const float*)d_in[1];
  const float* gamma  = (const float*)d_in[2];
  const float* beta   = (const float*)d_in[3];
  const int*   in_idx = (const int*)d_in[4];
  const int*   kidx   = (const int*)d_in[5];
  int M    = in_sizes[4];
  int N_IN = in_sizes[0] / CIN;
  float* out = (float*)d_out;

  float*  gsum  = (float*)((char*)d_ws + 128);
  float*  gsq   = (float*)((char*)d_ws + 384);
  __bf16* wfrag = (__bf16*)((char*)d_ws + 1024);
  int*    tbl   = (int*)((char*)d_ws + 66560);

  hipMemsetAsync(d_ws, 0, 1024, stream);
  hipMemsetAsync(tbl, 0xFF, (size_t)N_IN * KVOL * sizeof(int), stream);
  k_prepw<<<128, 256, 0, stream>>>(weight, wfrag);
  k_tbl<<<1024, 256, 0, stream>>>(in_idx, kidx, M, tbl);

  int nb = (N_IN + TP - 1) / TP;
  k_gemm<<<nb, 256, 0, stream>>>(feats, tbl, wfrag, out, gsum, gsq, N_IN);

  k_norm<<<2048, 256, 0, stream>>>(out, gsum, gsq, gamma, beta, M);
}